// Round 3
// baseline (261.604 us; speedup 1.0000x reference)
//
#include <hip/hip_runtime.h>
#include <hip/hip_bf16.h>
#include <stdint.h>

typedef __attribute__((ext_vector_type(8)))  short short8;
typedef __attribute__((ext_vector_type(8)))  unsigned short ushort8;
typedef __attribute__((ext_vector_type(4)))  float floatx4;
typedef __attribute__((ext_vector_type(4)))  int intx4;
typedef __attribute__((ext_vector_type(4)))  unsigned short ushortx4;

static constexpr int BATCH = 4;
static constexpr int SEQ   = 2048;
static constexpr int DIM   = 1024;
static constexpr int LDQ   = 3 * DIM;  // qkv row stride

typedef __attribute__((address_space(1))) unsigned int gas_u32;
typedef __attribute__((address_space(3))) unsigned int las_u32;
typedef __attribute__((address_space(3))) const __hip_bfloat16 lds_cbf16;

__device__ __forceinline__ void async_copy16(void* lds, const void* g) {
  __builtin_amdgcn_global_load_lds((const gas_u32*)g, (las_u32*)lds, 16, 0, 0);
}

// Inline-asm ds_read_b128: invisible to the backend's waitcnt insertion.
// NO "memory" clobber anywhere in the hot loop: a "memory"-clobbered asm
// makes SIWaitcnt treat the asm as "may read anything" and prepend a
// conservative vmcnt(0) drain -- which serialized the prefetch ring in
// rounds 1-2 (observed +3600 cyc/K-tile vs model). Ordering is done purely
// with counted waits + sched_barrier(0) fences (rule #18).
template<int OFF>
__device__ __forceinline__ short8 ds_read128(lds_cbf16* p) {
  short8 r;
  asm volatile("ds_read_b128 %0, %1 offset:%2" : "=v"(r) : "v"(p), "i"(OFF));
  return r;
}

__device__ __forceinline__ void wait_lgkm0() {
  asm volatile("s_waitcnt lgkmcnt(0)");     // bare: no memory clobber!
  __builtin_amdgcn_sched_barrier(0);        // rule #18: pin MFMA behind wait
}

template<int N>
__device__ __forceinline__ void wait_vm() {
  __builtin_amdgcn_sched_barrier(0);        // pin stage issues before the wait
  asm volatile("s_waitcnt vmcnt(%0)" :: "i"(N));
  __builtin_amdgcn_sched_barrier(0);        // pin subsequent reads after it
}

// ---------------------------------------------------------------------------
// Fused canonize (per-block fp32-vs-bf16 self-detection) + zero rowsum.
// ---------------------------------------------------------------------------
__global__ __launch_bounds__(256) void canonize_all(
    const void* __restrict__ s0, const void* __restrict__ s1,
    const void* __restrict__ s2, const void* __restrict__ s3,
    const void* __restrict__ s4, const void* __restrict__ s5,
    const void* __restrict__ s6,
    __hip_bfloat16* __restrict__ xc, __hip_bfloat16* __restrict__ Wc,
    __hip_bfloat16* __restrict__ bc, float* __restrict__ rowsum)
{
  int bid = blockIdx.x;
  if (bid >= 5635) {
    const int i = (bid - 5635) * 2048 + threadIdx.x * 8;
    intx4 z = {0, 0, 0, 0};
    *(intx4*)(rowsum + i)     = z;
    *(intx4*)(rowsum + i + 4) = z;
    return;
  }
  const void* src; __hip_bfloat16* dst; int n;
  if (bid < 4096)        { src = s0; dst = xc;            n = 8388608; }
  else if (bid < 4608)   { src = s1; dst = Wc;            n = 1048576; bid -= 4096; }
  else if (bid < 5120)   { src = s2; dst = Wc + 1048576;  n = 1048576; bid -= 4608; }
  else if (bid < 5632)   { src = s3; dst = Wc + 2097152;  n = 1048576; bid -= 5120; }
  else if (bid == 5632)  { src = s4; dst = bc;            n = 1024;    bid = 0; }
  else if (bid == 5633)  { src = s5; dst = bc + 1024;     n = 1024;    bid = 0; }
  else                   { src = s6; dst = bc + 2048;     n = 1024;    bid = 0; }

  __shared__ int cnt;
  if (threadIdx.x == 0) cnt = 0;
  __syncthreads();

  const int i = (bid * 256 + threadIdx.x) * 8;
  ushort8 v = {};
  int local = 0;
  if (i < n) {
    v = *(const ushort8*)((const unsigned short*)src + i);
#pragma unroll
    for (int j = 0; j < 8; j++) {
      unsigned e = (v[j] >> 7) & 0xFFu;
      local += (e >= 0x90u) ? 1 : 0;
    }
  }
  if (local) atomicAdd(&cnt, local);
  __syncthreads();
  if (i >= n) return;

  if (cnt > 4) {  // fp32 input: convert
    const float* s = (const float*)src + i;
    ushort8 o;
#pragma unroll
    for (int j = 0; j < 8; j++) {
      __hip_bfloat16 h = (__hip_bfloat16)s[j];
      o[j] = *(const unsigned short*)&h;
    }
    *(ushort8*)((unsigned short*)dst + i) = o;
  } else {        // already bf16: copy the probed data
    *(ushort8*)((unsigned short*)dst + i) = v;
  }
}

// ---------------------------------------------------------------------------
// 16-MFMA cluster: acc rows MI0,MI0+1 x 4 ni x 2 k-slices.
// ---------------------------------------------------------------------------
template<int MI0, int MR>
__device__ __forceinline__ void mfma_quad(floatx4 (&acc)[MR][4],
    const short8 (&fa)[2][2], const short8 (&fb)[2][4]) {
#pragma unroll
  for (int i = 0; i < 2; i++)
#pragma unroll
    for (int ni = 0; ni < 4; ni++)
#pragma unroll
      for (int ks = 0; ks < 2; ks++)
        acc[MI0 + i][ni] = __builtin_amdgcn_mfma_f32_16x16x32_bf16(
            fa[ks][i], fb[ks][ni], acc[MI0 + i][ni], 0, 0, 0);
}

// ---------------------------------------------------------------------------
// NT GEMM, 256x256 tile, BK=64, 512 threads = 8 waves (2M x 4N), per-wave
// 128x64 output. 4 phases per K-tile, derived waits (asm ds_read + counted
// vmcnt, ALL clobber-free; the only waits in the loop are ours):
//   P1: asm-read 8 B-frags + A{0,1} | stage A-half0(t+1)->buf^1
//   P2: asm-read A{2,3}             | stage A-half1(t+1)->buf^1
//   P3: asm-read A{4,5}             | stage B-half0(t+2)->buf
//   P4: asm-read A{6,7}             | stage B-half1(t+2)->buf
// phase = [reads; stage; s_barrier; lgkmcnt(0)+sched_barrier; setprio(1);
//          16 MFMA; setprio(0); s_barrier]; vmcnt(4) once per tile at P4
// (outstanding 12 = B(t+1)4 + A(t+1)4 + B(t+2)4; oldest 8 must land).
// WAR: A(t+1)->buf^1 ok after P4(t-1) barrier (A(t-1) reads lgkm-waited);
//      B(t+2)->buf ok after P1 barrier (B(t) frags register-resident).
// LDS row stride 64 elems; fragment slot (quad^(lm>>1)) + staging xor
// (tid&7)^((tid>>4)&7) are row-mod-16 consistent -> 0 bank conflicts.
// EPI: 0 = +bias[col] -> bf16 ; 1 = exp(acc/32) -> bf16 + rowsum atomics
// ---------------------------------------------------------------------------
template<int EPI>
__global__ __launch_bounds__(512, 2) void gemm256(
    const __hip_bfloat16* __restrict__ A,
    const __hip_bfloat16* __restrict__ B,
    const __hip_bfloat16* __restrict__ bias,
    float* __restrict__ rowsum,
    void* __restrict__ Cout,
    int M, int N, int K, int lda, int ldb,
    size_t sA, size_t sB, size_t sC)
{
  __shared__ __hip_bfloat16 As[2][256 * 64];
  __shared__ __hip_bfloat16 Bs[2][256 * 64];

  const int tid  = threadIdx.x;
  const int lane = tid & 63;
  const int wave = tid >> 6;
  const int wm   = (wave >> 2) * 128;
  const int wn   = (wave & 3) * 64;
  const int lm   = lane & 15;
  const int quad = lane >> 4;
  const int ch0  = (quad ^ (lm >> 1)) * 8;

  const size_t bz = blockIdx.z;
  A += bz * sA;
  B += bz * sB;
  const int m0 = blockIdx.y * 256;
  const int n0 = blockIdx.x * 256;

  const int rr = tid >> 3;
  const int jg = ((tid & 7) ^ ((tid >> 4) & 7)) * 8;
  const __hip_bfloat16* Ag = A + (size_t)(m0 + rr) * lda + jg;
  const __hip_bfloat16* Bg = B + (size_t)(n0 + rr) * ldb + jg;

  const int nt = K >> 6;
  floatx4 acc[8][4] = {};

  auto stageA = [&](int db, int kk, int h) {   // 128x64 half-tile, 2 insts
    const int ro = h * 128;
    async_copy16(&As[db][(ro)      * 64 + tid * 8], Ag + kk + (size_t)(ro)      * lda);
    async_copy16(&As[db][(ro + 64) * 64 + tid * 8], Ag + kk + (size_t)(ro + 64) * lda);
  };
  auto stageB = [&](int db, int kk, int h) {
    const int ro = h * 128;
    async_copy16(&Bs[db][(ro)      * 64 + tid * 8], Bg + kk + (size_t)(ro)      * ldb);
    async_copy16(&Bs[db][(ro + 64) * 64 + tid * 8], Bg + kk + (size_t)(ro + 64) * ldb);
  };

  // Prologue: tile 0 fully + B of tile 1; wait tile 0 (oldest 8), keep B(1).
  stageA(0, 0, 0); stageA(0, 0, 1);
  stageB(0, 0, 0); stageB(0, 0, 1);
  if (nt > 1) {
    stageB(1, 64, 0); stageB(1, 64, 1);
    wait_vm<4>();
  } else {
    wait_vm<0>();
  }
  __builtin_amdgcn_s_barrier();

  for (int t = 0; t < nt; ++t) {
    const int buf = t & 1;
    const int kb  = t * 64;
    const __hip_bfloat16* Ab = &As[buf][(wm + lm) * 64];
    const __hip_bfloat16* Bb = &Bs[buf][(wn + lm) * 64];
    lds_cbf16* a0 = (lds_cbf16*)(Ab + ch0);
    lds_cbf16* a1 = (lds_cbf16*)(Ab + (ch0 ^ 32));
    lds_cbf16* b0 = (lds_cbf16*)(Bb + ch0);
    lds_cbf16* b1 = (lds_cbf16*)(Bb + (ch0 ^ 32));
    short8 fa[2][2], fb[2][4];

    // ---- P1
    fb[0][0] = ds_read128<0>(b0);    fb[0][1] = ds_read128<2048>(b0);
    fb[0][2] = ds_read128<4096>(b0); fb[0][3] = ds_read128<6144>(b0);
    fb[1][0] = ds_read128<0>(b1);    fb[1][1] = ds_read128<2048>(b1);
    fb[1][2] = ds_read128<4096>(b1); fb[1][3] = ds_read128<6144>(b1);
    fa[0][0] = ds_read128<0>(a0);    fa[0][1] = ds_read128<2048>(a0);
    fa[1][0] = ds_read128<0>(a1);    fa[1][1] = ds_read128<2048>(a1);
    if (t + 1 < nt) stageA(buf ^ 1, kb + 64, 0);
    __builtin_amdgcn_s_barrier();
    wait_lgkm0();
    __builtin_amdgcn_s_setprio(1);
    mfma_quad<0>(acc, fa, fb);
    __builtin_amdgcn_s_setprio(0);
    __builtin_amdgcn_s_barrier();

    // ---- P2
    fa[0][0] = ds_read128<4096>(a0); fa[0][1] = ds_read128<6144>(a0);
    fa[1][0] = ds_read128<4096>(a1); fa[1][1] = ds_read128<6144>(a1);
    if (t + 1 < nt) stageA(buf ^ 1, kb + 64, 1);
    __builtin_amdgcn_s_barrier();
    wait_lgkm0();
    __builtin_amdgcn_s_setprio(1);
    mfma_quad<2>(acc, fa, fb);
    __builtin_amdgcn_s_setprio(0);
    __builtin_amdgcn_s_barrier();

    // ---- P3
    fa[0][0] = ds_read128<8192>(a0); fa[0][1] = ds_read128<10240>(a0);
    fa[1][0] = ds_read128<8192>(a1); fa[1][1] = ds_read128<10240>(a1);
    if (t + 2 < nt) stageB(buf, kb + 128, 0);
    __builtin_amdgcn_s_barrier();
    wait_lgkm0();
    __builtin_amdgcn_s_setprio(1);
    mfma_quad<4>(acc, fa, fb);
    __builtin_amdgcn_s_setprio(0);
    __builtin_amdgcn_s_barrier();

    // ---- P4 (+ counted vmcnt at tile boundary)
    fa[0][0] = ds_read128<12288>(a0); fa[0][1] = ds_read128<14336>(a0);
    fa[1][0] = ds_read128<12288>(a1); fa[1][1] = ds_read128<14336>(a1);
    if (t + 2 < nt) stageB(buf, kb + 128, 1);
    __builtin_amdgcn_s_barrier();
    wait_lgkm0();
    __builtin_amdgcn_s_setprio(1);
    mfma_quad<6>(acc, fa, fb);
    __builtin_amdgcn_s_setprio(0);
    if (t + 2 < nt)      wait_vm<4>();
    else if (t + 1 < nt) wait_vm<0>();
    __builtin_amdgcn_s_barrier();
  }

  // C/D layout: col = lane&15, row = quad*4 + i  [m89 verified]
  if constexpr (EPI == 1) {
    __hip_bfloat16* C = (__hip_bfloat16*)Cout + bz * sC;
    float* rs = rowsum + bz * (size_t)M;
    float ps[8][4];
#pragma unroll
    for (int mi = 0; mi < 8; mi++)
#pragma unroll
      for (int i = 0; i < 4; i++) ps[mi][i] = 0.0f;
#pragma unroll
    for (int mi = 0; mi < 8; mi++)
#pragma unroll
      for (int ni = 0; ni < 4; ni++) {
        const int col = n0 + wn + ni * 16 + lm;
#pragma unroll
        for (int i = 0; i < 4; i++) {
          const int row = m0 + wm + mi * 16 + quad * 4 + i;
          const float e = __expf(acc[mi][ni][i] * 0.03125f);
          C[(size_t)row * N + col] = (__hip_bfloat16)e;
          ps[mi][i] += e;
        }
      }
#pragma unroll
    for (int mi = 0; mi < 8; mi++)
#pragma unroll
      for (int i = 0; i < 4; i++) {
        float s = ps[mi][i];
        s += __shfl_xor(s, 1);
        s += __shfl_xor(s, 2);
        s += __shfl_xor(s, 4);
        s += __shfl_xor(s, 8);
        if (lm == 0) {
          const int row = m0 + wm + mi * 16 + quad * 4 + i;
          atomicAdd(&rs[row], s);
        }
      }
  } else {
    __hip_bfloat16* C = (__hip_bfloat16*)Cout + bz * sC;
#pragma unroll
    for (int ni = 0; ni < 4; ni++) {
      const int col = n0 + wn + ni * 16 + lm;
      const float bv = (float)bias[col];
#pragma unroll
      for (int mi = 0; mi < 8; mi++)
#pragma unroll
        for (int i = 0; i < 4; i++) {
          const int row = m0 + wm + mi * 16 + quad * 4 + i;
          C[(size_t)row * N + col] = (__hip_bfloat16)(acc[mi][ni][i] + bv);
        }
    }
  }
}

// ---------------------------------------------------------------------------
// NT GEMM, 128x256 tile, BK=64, 8 waves (2M x 4N), wave tile 64x64
// (acc[4][4]), 2 phases per K-tile. Same clobber-free derived-waits ring:
//   P1: asm-read 8 B-frags + A{0,1} | stage A(t+1) (2) -> buf^1
//   P2: asm-read A{2,3}             | stage B(t+2) (4) -> buf
//   vmcnt(4) at P2 end: outstanding 10 = B(t+1)4 + A(t+1)2 + B(t+2)4.
// 256-WG grid for PV (N=1024 -> only 4 col-blocks of 256). LDS 96 KiB.
// EPI: 2 = acc / rowsum[row] -> fp32.
// ---------------------------------------------------------------------------
template<int EPI>
__global__ __launch_bounds__(512, 2) void gemm128(
    const __hip_bfloat16* __restrict__ A,
    const __hip_bfloat16* __restrict__ B,
    float* __restrict__ rowsum,
    void* __restrict__ Cout,
    int M, int N, int K, int lda, int ldb,
    size_t sA, size_t sB, size_t sC)
{
  __shared__ __hip_bfloat16 As[2][128 * 64];
  __shared__ __hip_bfloat16 Bs[2][256 * 64];

  const int tid  = threadIdx.x;
  const int lane = tid & 63;
  const int wave = tid >> 6;
  const int wm   = (wave >> 2) * 64;
  const int wn   = (wave & 3) * 64;
  const int lm   = lane & 15;
  const int quad = lane >> 4;
  const int ch0  = (quad ^ (lm >> 1)) * 8;

  const size_t bz = blockIdx.z;
  A += bz * sA;
  B += bz * sB;
  const int m0 = blockIdx.y * 128;
  const int n0 = blockIdx.x * 256;

  const int rr = tid >> 3;
  const int jg = ((tid & 7) ^ ((tid >> 4) & 7)) * 8;
  const __hip_bfloat16* Ag = A + (size_t)(m0 + rr) * lda + jg;
  const __hip_bfloat16* Bg = B + (size_t)(n0 + rr) * ldb + jg;

  const int nt = K >> 6;
  floatx4 acc[4][4] = {};

  auto stageA = [&](int db, int kk) {          // 128x64 tile, 2 insts
    async_copy16(&As[db][tid * 8],        Ag + kk);
    async_copy16(&As[db][4096 + tid * 8], Ag + kk + (size_t)64 * lda);
  };
  auto stageB = [&](int db, int kk) {          // 256x64 tile, 4 insts
#pragma unroll
    for (int g = 0; g < 4; g++)
      async_copy16(&Bs[db][g * 4096 + tid * 8], Bg + kk + (size_t)(g * 64) * ldb);
  };

  stageA(0, 0);
  stageB(0, 0);
  if (nt > 1) {
    stageB(1, 64);
    wait_vm<4>();
  } else {
    wait_vm<0>();
  }
  __builtin_amdgcn_s_barrier();

  for (int t = 0; t < nt; ++t) {
    const int buf = t & 1;
    const int kb  = t * 64;
    const __hip_bfloat16* Ab = &As[buf][(wm + lm) * 64];
    const __hip_bfloat16* Bb = &Bs[buf][(wn + lm) * 64];
    lds_cbf16* a0 = (lds_cbf16*)(Ab + ch0);
    lds_cbf16* a1 = (lds_cbf16*)(Ab + (ch0 ^ 32));
    lds_cbf16* b0 = (lds_cbf16*)(Bb + ch0);
    lds_cbf16* b1 = (lds_cbf16*)(Bb + (ch0 ^ 32));
    short8 fa[2][2], fb[2][4];

    // ---- P1
    fb[0][0] = ds_read128<0>(b0);    fb[0][1] = ds_read128<2048>(b0);
    fb[0][2] = ds_read128<4096>(b0); fb[0][3] = ds_read128<6144>(b0);
    fb[1][0] = ds_read128<0>(b1);    fb[1][1] = ds_read128<2048>(b1);
    fb[1][2] = ds_read128<4096>(b1); fb[1][3] = ds_read128<6144>(b1);
    fa[0][0] = ds_read128<0>(a0);    fa[0][1] = ds_read128<2048>(a0);
    fa[1][0] = ds_read128<0>(a1);    fa[1][1] = ds_read128<2048>(a1);
    if (t + 1 < nt) stageA(buf ^ 1, kb + 64);
    __builtin_amdgcn_s_barrier();
    wait_lgkm0();
    __builtin_amdgcn_s_setprio(1);
    mfma_quad<0>(acc, fa, fb);
    __builtin_amdgcn_s_setprio(0);
    __builtin_amdgcn_s_barrier();

    // ---- P2 (+ counted vmcnt at tile boundary)
    fa[0][0] = ds_read128<4096>(a0); fa[0][1] = ds_read128<6144>(a0);
    fa[1][0] = ds_read128<4096>(a1); fa[1][1] = ds_read128<6144>(a1);
    if (t + 2 < nt) stageB(buf, kb + 128);
    __builtin_amdgcn_s_barrier();
    wait_lgkm0();
    __builtin_amdgcn_s_setprio(1);
    mfma_quad<2>(acc, fa, fb);
    __builtin_amdgcn_s_setprio(0);
    if (t + 2 < nt)      wait_vm<4>();
    else if (t + 1 < nt) wait_vm<0>();
    __builtin_amdgcn_s_barrier();
  }

  if constexpr (EPI == 2) {
    float* C = (float*)Cout + bz * sC;
    const float* rs = rowsum + bz * (size_t)M;
#pragma unroll
    for (int mi = 0; mi < 4; mi++)
#pragma unroll
      for (int i = 0; i < 4; i++) {
        const int row = m0 + wm + mi * 16 + quad * 4 + i;
        const float rv = 1.0f / rs[row];
#pragma unroll
        for (int ni = 0; ni < 4; ni++) {
          const int col = n0 + wn + ni * 16 + lm;
          C[(size_t)row * N + col] = acc[mi][ni][i] * rv;
        }
      }
  }
}

// ---------------------------------------------------------------------------
// vT[b][e][s] = qkv[b][s][2048 + e]
// ---------------------------------------------------------------------------
__global__ __launch_bounds__(256) void transpose_v(
    const __hip_bfloat16* __restrict__ qkv, __hip_bfloat16* __restrict__ vT)
{
  __shared__ unsigned short t[64][68];
  const size_t bz = blockIdx.z;
  const unsigned short* src = (const unsigned short*)(qkv + bz * (size_t)SEQ * LDQ + 2048);
  unsigned short* dst = (unsigned short*)(vT + bz * (size_t)DIM * SEQ);
  const int e0 = blockIdx.x * 64;
  const int s0 = blockIdx.y * 64;
  const int tid = threadIdx.x;
  const int tr = tid >> 4;
  const int tc = (tid & 15) * 4;

#pragma unroll
  for (int i = 0; i < 4; i++) {
    const int row = tr + i * 16;
    ushortx4 val = *(const ushortx4*)(src + (size_t)(s0 + row) * LDQ + e0 + tc);
    t[row][tc + 0] = val.x; t[row][tc + 1] = val.y;
    t[row][tc + 2] = val.z; t[row][tc + 3] = val.w;
  }
  __syncthreads();
#pragma unroll
  for (int i = 0; i < 4; i++) {
    const int row = tr + i * 16;
    ushortx4 val;
    val.x = t[tc + 0][row]; val.y = t[tc + 1][row];
    val.z = t[tc + 2][row]; val.w = t[tc + 3][row];
    *(ushortx4*)(dst + (size_t)(e0 + row) * SEQ + s0 + tc) = val;
  }
}

// ---------------------------------------------------------------------------
extern "C" void kernel_launch(void* const* d_in, const int* in_sizes, int n_in,
                              void* d_out, int out_size, void* d_ws, size_t ws_size,
                              hipStream_t stream) {
  char* ws = (char*)d_ws;
  const size_t MB = 1024 * 1024;

  __hip_bfloat16* xc     = (__hip_bfloat16*)(ws + 1 * MB);   // 16 MB [1,17)
  __hip_bfloat16* Wc     = (__hip_bfloat16*)(ws + 17 * MB);  // 6 MB  [17,23)
  __hip_bfloat16* bc     = (__hip_bfloat16*)(ws + 23 * MB);  // 6 KB
  __hip_bfloat16* P      = (__hip_bfloat16*)(ws + 1 * MB);   // 32 MB [1,33) (after QKV)
  __hip_bfloat16* qkv    = (__hip_bfloat16*)(ws + 33 * MB);  // 48 MB [33,81)
  __hip_bfloat16* vT     = (__hip_bfloat16*)(ws + 81 * MB);  // 16 MB [81,97)
  float*          rowsum = (float*)(ws + 97 * MB);           // 32 KB
  float*          out    = (float*)d_out;

  const int NT = BATCH * SEQ;  // 8192

  canonize_all<<<dim3(5639), 256, 0, stream>>>(
      d_in[0], d_in[1], d_in[3], d_in[5], d_in[2], d_in[4], d_in[6],
      xc, Wc, bc, rowsum);

  // Fused QKV projection: [8192 x 3072] = x @ [Wq;Wk;Wv]^T + [bq;bk;bv]
  gemm256<0><<<dim3(3 * DIM / 256, NT / 256, 1), 512, 0, stream>>>(
      xc, Wc, bc, nullptr, qkv, NT, 3 * DIM, DIM, DIM, DIM, 0, 0, 0);

  transpose_v<<<dim3(DIM / 64, SEQ / 64, BATCH), 256, 0, stream>>>(qkv, vT);

  // P[b] = exp(q[b] @ k[b]^T / 32), rowsum accumulated in epilogue
  gemm256<1><<<dim3(SEQ / 256, SEQ / 256, BATCH), 512, 0, stream>>>(
      qkv /*q*/, qkv + DIM /*k*/, nullptr, rowsum, P, SEQ, SEQ, DIM, LDQ, LDQ,
      (size_t)SEQ * LDQ, (size_t)SEQ * LDQ, (size_t)SEQ * SEQ);

  // out[b] = (P[b] @ v[b]) / rowsum — 128x256 tile -> 4x16x4 = 256 WGs
  gemm128<2><<<dim3(DIM / 256, SEQ / 128, BATCH), 512, 0, stream>>>(
      P, vT, rowsum, out, SEQ, DIM, SEQ, SEQ, SEQ,
      (size_t)SEQ * SEQ, (size_t)DIM * SEQ, (size_t)SEQ * DIM);
}

// Round 4
// 253.586 us; speedup vs baseline: 1.0316x; 1.0316x over previous
//
#include <hip/hip_runtime.h>
#include <hip/hip_bf16.h>
#include <stdint.h>

typedef __attribute__((ext_vector_type(8)))  short short8;
typedef __attribute__((ext_vector_type(8)))  unsigned short ushort8;
typedef __attribute__((ext_vector_type(4)))  float floatx4;
typedef __attribute__((ext_vector_type(4)))  int intx4;
typedef __attribute__((ext_vector_type(4)))  unsigned short ushortx4;

static constexpr int BATCH = 4;
static constexpr int SEQ   = 2048;
static constexpr int DIM   = 1024;
static constexpr int LDQ   = 3 * DIM;  // qkv row stride

typedef __attribute__((address_space(1))) unsigned int gas_u32;
typedef __attribute__((address_space(3))) unsigned int las_u32;
typedef __attribute__((address_space(3))) const __hip_bfloat16 lds_cbf16;

__device__ __forceinline__ void async_copy16(void* lds, const void* g) {
  __builtin_amdgcn_global_load_lds((const gas_u32*)g, (las_u32*)lds, 16, 0, 0);
}

// Inline-asm ds_read_b128: invisible to the backend's waitcnt insertion
// (keeps the global_load_lds prefetch ring in flight). volatile (not
// "memory"-clobbered): ordered vs other volatile asm and side-effecting
// intrinsics (s_barrier, global_load_lds), but pure MFMA intrinsics may
// interleave with it -- exactly what we want (m196: fine
// ds_read || G::load || MFMA interleave is the lever).
template<int OFF>
__device__ __forceinline__ short8 ds_read128(lds_cbf16* p) {
  short8 r;
  asm volatile("ds_read_b128 %0, %1 offset:%2" : "=v"(r) : "v"(p), "i"(OFF));
  return r;
}

__device__ __forceinline__ void wait_lgkm0() {
  asm volatile("s_waitcnt lgkmcnt(0)");     // bare: no memory clobber
  __builtin_amdgcn_sched_barrier(0);        // rule #18: pin MFMA behind wait
}

// ---------------------------------------------------------------------------
// Fused canonize (per-block fp32-vs-bf16 self-detection) + zero rowsum.
// ---------------------------------------------------------------------------
__global__ __launch_bounds__(256) void canonize_all(
    const void* __restrict__ s0, const void* __restrict__ s1,
    const void* __restrict__ s2, const void* __restrict__ s3,
    const void* __restrict__ s4, const void* __restrict__ s5,
    const void* __restrict__ s6,
    __hip_bfloat16* __restrict__ xc, __hip_bfloat16* __restrict__ Wc,
    __hip_bfloat16* __restrict__ bc, float* __restrict__ rowsum)
{
  int bid = blockIdx.x;
  if (bid >= 5635) {
    const int i = (bid - 5635) * 2048 + threadIdx.x * 8;
    intx4 z = {0, 0, 0, 0};
    *(intx4*)(rowsum + i)     = z;
    *(intx4*)(rowsum + i + 4) = z;
    return;
  }
  const void* src; __hip_bfloat16* dst; int n;
  if (bid < 4096)        { src = s0; dst = xc;            n = 8388608; }
  else if (bid < 4608)   { src = s1; dst = Wc;            n = 1048576; bid -= 4096; }
  else if (bid < 5120)   { src = s2; dst = Wc + 1048576;  n = 1048576; bid -= 4608; }
  else if (bid < 5632)   { src = s3; dst = Wc + 2097152;  n = 1048576; bid -= 5120; }
  else if (bid == 5632)  { src = s4; dst = bc;            n = 1024;    bid = 0; }
  else if (bid == 5633)  { src = s5; dst = bc + 1024;     n = 1024;    bid = 0; }
  else                   { src = s6; dst = bc + 2048;     n = 1024;    bid = 0; }

  __shared__ int cnt;
  if (threadIdx.x == 0) cnt = 0;
  __syncthreads();

  const int i = (bid * 256 + threadIdx.x) * 8;
  ushort8 v = {};
  int local = 0;
  if (i < n) {
    v = *(const ushort8*)((const unsigned short*)src + i);
#pragma unroll
    for (int j = 0; j < 8; j++) {
      unsigned e = (v[j] >> 7) & 0xFFu;
      local += (e >= 0x90u) ? 1 : 0;
    }
  }
  if (local) atomicAdd(&cnt, local);
  __syncthreads();
  if (i >= n) return;

  if (cnt > 4) {  // fp32 input: convert
    const float* s = (const float*)src + i;
    ushort8 o;
#pragma unroll
    for (int j = 0; j < 8; j++) {
      __hip_bfloat16 h = (__hip_bfloat16)s[j];
      o[j] = *(const unsigned short*)&h;
    }
    *(ushort8*)((unsigned short*)dst + i) = o;
  } else {        // already bf16: copy the probed data
    *(ushort8*)((unsigned short*)dst + i) = v;
  }
}

// ---------------------------------------------------------------------------
// 16-MFMA cluster: acc rows MI0,MI0+1 x 4 ni x 2 k-slices.
// ---------------------------------------------------------------------------
template<int MI0, int MR>
__device__ __forceinline__ void mfma_quad(floatx4 (&acc)[MR][4],
    const short8 (&fa)[2][2], const short8 (&fb)[2][4]) {
#pragma unroll
  for (int i = 0; i < 2; i++)
#pragma unroll
    for (int ni = 0; ni < 4; ni++)
#pragma unroll
      for (int ks = 0; ks < 2; ks++)
        acc[MI0 + i][ni] = __builtin_amdgcn_mfma_f32_16x16x32_bf16(
            fa[ks][i], fb[ks][ni], acc[MI0 + i][ni], 0, 0, 0);
}

// ---------------------------------------------------------------------------
// NT GEMM, 256x256 tile, BK=64, 512 threads = 8 waves (2M x 4N), per-wave
// 128x64 output, 4 MFMA quads per K-tile, TWO barriers per K-tile:
//
//   [boundary barrier] -> burst-read fb(8)+faA(4); gate; quad0
//     shadow: faB(mi2,3) reads + stageA(t+1,h0)     (interleaved into quad0)
//   gate; quad1
//     shadow: faA(mi4,5) reads + stageA(t+1,h1)
//   BARRIER-1  (certifies all waves' fb reads done -> B(t+2) WAR-safe)
//   gate; quad2
//     shadow: faB(mi6,7) reads + stageB(t+2,h0)
//   gate; quad3
//     shadow: stageB(t+2,h1)
//   sched_barrier; vmcnt(4); barrier   (tile boundary: per-wave counted wait
//                                       THEN barrier => all waves' t+1 DMAs
//                                       certified landed for everyone)
//
// WAR legality: stageA targets buf^1 (A(t-1) readers certified by the t-1
// boundary barrier); stageB targets buf but only after BARRIER-1, and fb
// reads (the only B readers) completed before each wave's quad0 gate.
// RAW: per-wave vmcnt(4) BEFORE the boundary barrier => barrier exit
// certifies every wave's A(t+1)/B(t+1) DMAs landed (vmcnt is per-wave!).
// Ring: during t stage A(t+1)(4)+B(t+2)(4); at boundary outstanding 12
// = B(t+1)4+A(t+1)4+B(t+2)4 -> vmcnt(4) lands tile t+1, keeps B(t+2).
// Fragment slot (quad^(lm>>1)) + staging xor (tid&7)^((tid>>4)&7) are
// row-mod-16 consistent -> 0 LDS bank conflicts (measured).
// EPI: 0 = +bias[col] -> bf16 ; 1 = exp(acc/32) -> bf16 + rowsum atomics
// ---------------------------------------------------------------------------
template<int EPI>
__global__ __launch_bounds__(512, 2) void gemm256(
    const __hip_bfloat16* __restrict__ A,
    const __hip_bfloat16* __restrict__ B,
    const __hip_bfloat16* __restrict__ bias,
    float* __restrict__ rowsum,
    void* __restrict__ Cout,
    int M, int N, int K, int lda, int ldb,
    size_t sA, size_t sB, size_t sC)
{
  __shared__ __hip_bfloat16 As[2][256 * 64];
  __shared__ __hip_bfloat16 Bs[2][256 * 64];

  const int tid  = threadIdx.x;
  const int lane = tid & 63;
  const int wave = tid >> 6;
  const int wm   = (wave >> 2) * 128;
  const int wn   = (wave & 3) * 64;
  const int lm   = lane & 15;
  const int quad = lane >> 4;
  const int ch0  = (quad ^ (lm >> 1)) * 8;

  const size_t bz = blockIdx.z;
  A += bz * sA;
  B += bz * sB;
  const int m0 = blockIdx.y * 256;
  const int n0 = blockIdx.x * 256;

  const int rr = tid >> 3;
  const int jg = ((tid & 7) ^ ((tid >> 4) & 7)) * 8;
  const __hip_bfloat16* Ag = A + (size_t)(m0 + rr) * lda + jg;
  const __hip_bfloat16* Bg = B + (size_t)(n0 + rr) * ldb + jg;

  const int nt = K >> 6;
  floatx4 acc[8][4] = {};

  auto stageA = [&](int db, int kk, int h) {   // 128x64 half-tile, 2 insts
    const int ro = h * 128;
    async_copy16(&As[db][(ro)      * 64 + tid * 8], Ag + kk + (size_t)(ro)      * lda);
    async_copy16(&As[db][(ro + 64) * 64 + tid * 8], Ag + kk + (size_t)(ro + 64) * lda);
  };
  auto stageB = [&](int db, int kk, int h) {
    const int ro = h * 128;
    async_copy16(&Bs[db][(ro)      * 64 + tid * 8], Bg + kk + (size_t)(ro)      * ldb);
    async_copy16(&Bs[db][(ro + 64) * 64 + tid * 8], Bg + kk + (size_t)(ro + 64) * ldb);
  };

  // Prologue: tile 0 fully + B of tile 1; wait tile 0 (oldest 8), keep B(1).
  stageA(0, 0, 0); stageA(0, 0, 1);
  stageB(0, 0, 0); stageB(0, 0, 1);
  if (nt > 1) {
    stageB(1, 64, 0); stageB(1, 64, 1);
    __builtin_amdgcn_sched_barrier(0);
    asm volatile("s_waitcnt vmcnt(4)");
  } else {
    __builtin_amdgcn_sched_barrier(0);
    asm volatile("s_waitcnt vmcnt(0)");
  }
  __builtin_amdgcn_s_barrier();

  for (int t = 0; t < nt; ++t) {
    const int buf = t & 1;
    const int kb  = t * 64;
    const __hip_bfloat16* Ab = &As[buf][(wm + lm) * 64];
    const __hip_bfloat16* Bb = &Bs[buf][(wn + lm) * 64];
    lds_cbf16* a0 = (lds_cbf16*)(Ab + ch0);
    lds_cbf16* a1 = (lds_cbf16*)(Ab + (ch0 ^ 32));
    lds_cbf16* b0 = (lds_cbf16*)(Bb + ch0);
    lds_cbf16* b1 = (lds_cbf16*)(Bb + (ch0 ^ 32));
    short8 fb[2][4], faA[2][2], faB[2][2];

    // ---- P1 burst: all B frags + A(mi0,1)
    fb[0][0] = ds_read128<0>(b0);    fb[0][1] = ds_read128<2048>(b0);
    fb[0][2] = ds_read128<4096>(b0); fb[0][3] = ds_read128<6144>(b0);
    fb[1][0] = ds_read128<0>(b1);    fb[1][1] = ds_read128<2048>(b1);
    fb[1][2] = ds_read128<4096>(b1); fb[1][3] = ds_read128<6144>(b1);
    faA[0][0] = ds_read128<0>(a0);   faA[0][1] = ds_read128<2048>(a0);
    faA[1][0] = ds_read128<0>(a1);   faA[1][1] = ds_read128<2048>(a1);
    wait_lgkm0();
    __builtin_amdgcn_s_setprio(1);
    mfma_quad<0>(acc, faA, fb);
    __builtin_amdgcn_s_setprio(0);
    // quad0 shadow: next A frags + stage (scheduler interleaves into quad0)
    faB[0][0] = ds_read128<4096>(a0); faB[0][1] = ds_read128<6144>(a0);
    faB[1][0] = ds_read128<4096>(a1); faB[1][1] = ds_read128<6144>(a1);
    if (t + 1 < nt) stageA(buf ^ 1, kb + 64, 0);

    wait_lgkm0();
    __builtin_amdgcn_s_setprio(1);
    mfma_quad<2>(acc, faB, fb);
    __builtin_amdgcn_s_setprio(0);
    faA[0][0] = ds_read128<8192>(a0); faA[0][1] = ds_read128<10240>(a0);
    faA[1][0] = ds_read128<8192>(a1); faA[1][1] = ds_read128<10240>(a1);
    if (t + 1 < nt) stageA(buf ^ 1, kb + 64, 1);

    __builtin_amdgcn_s_barrier();   // BARRIER-1: fb reads certified complete

    wait_lgkm0();
    __builtin_amdgcn_s_setprio(1);
    mfma_quad<4>(acc, faA, fb);
    __builtin_amdgcn_s_setprio(0);
    faB[0][0] = ds_read128<12288>(a0); faB[0][1] = ds_read128<14336>(a0);
    faB[1][0] = ds_read128<12288>(a1); faB[1][1] = ds_read128<14336>(a1);
    if (t + 2 < nt) stageB(buf, kb + 128, 0);

    wait_lgkm0();
    __builtin_amdgcn_s_setprio(1);
    mfma_quad<6>(acc, faB, fb);
    __builtin_amdgcn_s_setprio(0);
    if (t + 2 < nt) stageB(buf, kb + 128, 1);

    // ---- tile boundary: counted per-wave wait, THEN barrier
    __builtin_amdgcn_sched_barrier(0);
    if (t + 2 < nt)      asm volatile("s_waitcnt vmcnt(4)");
    else if (t + 1 < nt) asm volatile("s_waitcnt vmcnt(0)");
    __builtin_amdgcn_s_barrier();
  }

  // C/D layout: col = lane&15, row = quad*4 + i  [m89 verified]
  if constexpr (EPI == 1) {
    __hip_bfloat16* C = (__hip_bfloat16*)Cout + bz * sC;
    float* rs = rowsum + bz * (size_t)M;
    float ps[8][4];
#pragma unroll
    for (int mi = 0; mi < 8; mi++)
#pragma unroll
      for (int i = 0; i < 4; i++) ps[mi][i] = 0.0f;
#pragma unroll
    for (int mi = 0; mi < 8; mi++)
#pragma unroll
      for (int ni = 0; ni < 4; ni++) {
        const int col = n0 + wn + ni * 16 + lm;
#pragma unroll
        for (int i = 0; i < 4; i++) {
          const int row = m0 + wm + mi * 16 + quad * 4 + i;
          const float e = __expf(acc[mi][ni][i] * 0.03125f);
          C[(size_t)row * N + col] = (__hip_bfloat16)e;
          ps[mi][i] += e;
        }
      }
#pragma unroll
    for (int mi = 0; mi < 8; mi++)
#pragma unroll
      for (int i = 0; i < 4; i++) {
        float s = ps[mi][i];
        s += __shfl_xor(s, 1);
        s += __shfl_xor(s, 2);
        s += __shfl_xor(s, 4);
        s += __shfl_xor(s, 8);
        if (lm == 0) {
          const int row = m0 + wm + mi * 16 + quad * 4 + i;
          atomicAdd(&rs[row], s);
        }
      }
  } else {
    __hip_bfloat16* C = (__hip_bfloat16*)Cout + bz * sC;
#pragma unroll
    for (int ni = 0; ni < 4; ni++) {
      const int col = n0 + wn + ni * 16 + lm;
      const float bv = (float)bias[col];
#pragma unroll
      for (int mi = 0; mi < 8; mi++)
#pragma unroll
        for (int i = 0; i < 4; i++) {
          const int row = m0 + wm + mi * 16 + quad * 4 + i;
          C[(size_t)row * N + col] = (__hip_bfloat16)(acc[mi][ni][i] + bv);
        }
    }
  }
}

// ---------------------------------------------------------------------------
// NT GEMM, 128x256 tile, BK=64, 8 waves (2M x 4N), wave tile 64x64
// (acc[4][4]), 2 MFMA quads per K-tile, same 2-barrier schedule:
//   burst fb(8)+faA(4); gate; quad0 [shadow: faB(4) + stageA(t+1)(2)]
//   BARRIER-1; gate; quad1 [shadow: stageB(t+2)(4)]
//   sched_barrier; vmcnt(4); barrier
// Ring: outstanding at boundary 10 = B(t+1)4+A(t+1)2+B(t+2)4 -> vmcnt(4).
// 256-WG grid for PV (N=1024). LDS 96 KiB. EPI 2 = acc/rowsum[row] -> fp32.
// ---------------------------------------------------------------------------
template<int EPI>
__global__ __launch_bounds__(512, 2) void gemm128(
    const __hip_bfloat16* __restrict__ A,
    const __hip_bfloat16* __restrict__ B,
    float* __restrict__ rowsum,
    void* __restrict__ Cout,
    int M, int N, int K, int lda, int ldb,
    size_t sA, size_t sB, size_t sC)
{
  __shared__ __hip_bfloat16 As[2][128 * 64];
  __shared__ __hip_bfloat16 Bs[2][256 * 64];

  const int tid  = threadIdx.x;
  const int lane = tid & 63;
  const int wave = tid >> 6;
  const int wm   = (wave >> 2) * 64;
  const int wn   = (wave & 3) * 64;
  const int lm   = lane & 15;
  const int quad = lane >> 4;
  const int ch0  = (quad ^ (lm >> 1)) * 8;

  const size_t bz = blockIdx.z;
  A += bz * sA;
  B += bz * sB;
  const int m0 = blockIdx.y * 128;
  const int n0 = blockIdx.x * 256;

  const int rr = tid >> 3;
  const int jg = ((tid & 7) ^ ((tid >> 4) & 7)) * 8;
  const __hip_bfloat16* Ag = A + (size_t)(m0 + rr) * lda + jg;
  const __hip_bfloat16* Bg = B + (size_t)(n0 + rr) * ldb + jg;

  const int nt = K >> 6;
  floatx4 acc[4][4] = {};

  auto stageA = [&](int db, int kk) {          // 128x64 tile, 2 insts
    async_copy16(&As[db][tid * 8],        Ag + kk);
    async_copy16(&As[db][4096 + tid * 8], Ag + kk + (size_t)64 * lda);
  };
  auto stageB = [&](int db, int kk) {          // 256x64 tile, 4 insts
#pragma unroll
    for (int g = 0; g < 4; g++)
      async_copy16(&Bs[db][g * 4096 + tid * 8], Bg + kk + (size_t)(g * 64) * ldb);
  };

  stageA(0, 0);
  stageB(0, 0);
  if (nt > 1) {
    stageB(1, 64);
    __builtin_amdgcn_sched_barrier(0);
    asm volatile("s_waitcnt vmcnt(4)");
  } else {
    __builtin_amdgcn_sched_barrier(0);
    asm volatile("s_waitcnt vmcnt(0)");
  }
  __builtin_amdgcn_s_barrier();

  for (int t = 0; t < nt; ++t) {
    const int buf = t & 1;
    const int kb  = t * 64;
    const __hip_bfloat16* Ab = &As[buf][(wm + lm) * 64];
    const __hip_bfloat16* Bb = &Bs[buf][(wn + lm) * 64];
    lds_cbf16* a0 = (lds_cbf16*)(Ab + ch0);
    lds_cbf16* a1 = (lds_cbf16*)(Ab + (ch0 ^ 32));
    lds_cbf16* b0 = (lds_cbf16*)(Bb + ch0);
    lds_cbf16* b1 = (lds_cbf16*)(Bb + (ch0 ^ 32));
    short8 fb[2][4], faA[2][2], faB[2][2];

    fb[0][0] = ds_read128<0>(b0);    fb[0][1] = ds_read128<2048>(b0);
    fb[0][2] = ds_read128<4096>(b0); fb[0][3] = ds_read128<6144>(b0);
    fb[1][0] = ds_read128<0>(b1);    fb[1][1] = ds_read128<2048>(b1);
    fb[1][2] = ds_read128<4096>(b1); fb[1][3] = ds_read128<6144>(b1);
    faA[0][0] = ds_read128<0>(a0);   faA[0][1] = ds_read128<2048>(a0);
    faA[1][0] = ds_read128<0>(a1);   faA[1][1] = ds_read128<2048>(a1);
    wait_lgkm0();
    __builtin_amdgcn_s_setprio(1);
    mfma_quad<0>(acc, faA, fb);
    __builtin_amdgcn_s_setprio(0);
    faB[0][0] = ds_read128<4096>(a0); faB[0][1] = ds_read128<6144>(a0);
    faB[1][0] = ds_read128<4096>(a1); faB[1][1] = ds_read128<6144>(a1);
    if (t + 1 < nt) stageA(buf ^ 1, kb + 64);

    __builtin_amdgcn_s_barrier();   // BARRIER-1: fb reads certified complete

    wait_lgkm0();
    __builtin_amdgcn_s_setprio(1);
    mfma_quad<2>(acc, faB, fb);
    __builtin_amdgcn_s_setprio(0);
    if (t + 2 < nt) stageB(buf, kb + 128);

    __builtin_amdgcn_sched_barrier(0);
    if (t + 2 < nt)      asm volatile("s_waitcnt vmcnt(4)");
    else if (t + 1 < nt) asm volatile("s_waitcnt vmcnt(0)");
    __builtin_amdgcn_s_barrier();
  }

  if constexpr (EPI == 2) {
    float* C = (float*)Cout + bz * sC;
    const float* rs = rowsum + bz * (size_t)M;
#pragma unroll
    for (int mi = 0; mi < 4; mi++)
#pragma unroll
      for (int i = 0; i < 4; i++) {
        const int row = m0 + wm + mi * 16 + quad * 4 + i;
        const float rv = 1.0f / rs[row];
#pragma unroll
        for (int ni = 0; ni < 4; ni++) {
          const int col = n0 + wn + ni * 16 + lm;
          C[(size_t)row * N + col] = acc[mi][ni][i] * rv;
        }
      }
  }
}

// ---------------------------------------------------------------------------
// vT[b][e][s] = qkv[b][s][2048 + e]
// ---------------------------------------------------------------------------
__global__ __launch_bounds__(256) void transpose_v(
    const __hip_bfloat16* __restrict__ qkv, __hip_bfloat16* __restrict__ vT)
{
  __shared__ unsigned short t[64][68];
  const size_t bz = blockIdx.z;
  const unsigned short* src = (const unsigned short*)(qkv + bz * (size_t)SEQ * LDQ + 2048);
  unsigned short* dst = (unsigned short*)(vT + bz * (size_t)DIM * SEQ);
  const int e0 = blockIdx.x * 64;
  const int s0 = blockIdx.y * 64;
  const int tid = threadIdx.x;
  const int tr = tid >> 4;
  const int tc = (tid & 15) * 4;

#pragma unroll
  for (int i = 0; i < 4; i++) {
    const int row = tr + i * 16;
    ushortx4 val = *(const ushortx4*)(src + (size_t)(s0 + row) * LDQ + e0 + tc);
    t[row][tc + 0] = val.x; t[row][tc + 1] = val.y;
    t[row][tc + 2] = val.z; t[row][tc + 3] = val.w;
  }
  __syncthreads();
#pragma unroll
  for (int i = 0; i < 4; i++) {
    const int row = tr + i * 16;
    ushortx4 val;
    val.x = t[tc + 0][row]; val.y = t[tc + 1][row];
    val.z = t[tc + 2][row]; val.w = t[tc + 3][row];
    *(ushortx4*)(dst + (size_t)(e0 + row) * SEQ + s0 + tc) = val;
  }
}

// ---------------------------------------------------------------------------
extern "C" void kernel_launch(void* const* d_in, const int* in_sizes, int n_in,
                              void* d_out, int out_size, void* d_ws, size_t ws_size,
                              hipStream_t stream) {
  char* ws = (char*)d_ws;
  const size_t MB = 1024 * 1024;

  __hip_bfloat16* xc     = (__hip_bfloat16*)(ws + 1 * MB);   // 16 MB [1,17)
  __hip_bfloat16* Wc     = (__hip_bfloat16*)(ws + 17 * MB);  // 6 MB  [17,23)
  __hip_bfloat16* bc     = (__hip_bfloat16*)(ws + 23 * MB);  // 6 KB
  __hip_bfloat16* P      = (__hip_bfloat16*)(ws + 1 * MB);   // 32 MB [1,33) (after QKV)
  __hip_bfloat16* qkv    = (__hip_bfloat16*)(ws + 33 * MB);  // 48 MB [33,81)
  __hip_bfloat16* vT     = (__hip_bfloat16*)(ws + 81 * MB);  // 16 MB [81,97)
  float*          rowsum = (float*)(ws + 97 * MB);           // 32 KB
  float*          out    = (float*)d_out;

  const int NT = BATCH * SEQ;  // 8192

  canonize_all<<<dim3(5639), 256, 0, stream>>>(
      d_in[0], d_in[1], d_in[3], d_in[5], d_in[2], d_in[4], d_in[6],
      xc, Wc, bc, rowsum);

  // Fused QKV projection: [8192 x 3072] = x @ [Wq;Wk;Wv]^T + [bq;bk;bv]
  gemm256<0><<<dim3(3 * DIM / 256, NT / 256, 1), 512, 0, stream>>>(
      xc, Wc, bc, nullptr, qkv, NT, 3 * DIM, DIM, DIM, DIM, 0, 0, 0);

  transpose_v<<<dim3(DIM / 64, SEQ / 64, BATCH), 256, 0, stream>>>(qkv, vT);

  // P[b] = exp(q[b] @ k[b]^T / 32), rowsum accumulated in epilogue
  gemm256<1><<<dim3(SEQ / 256, SEQ / 256, BATCH), 512, 0, stream>>>(
      qkv /*q*/, qkv + DIM /*k*/, nullptr, rowsum, P, SEQ, SEQ, DIM, LDQ, LDQ,
      (size_t)SEQ * LDQ, (size_t)SEQ * LDQ, (size_t)SEQ * SEQ);

  // out[b] = (P[b] @ v[b]) / rowsum — 128x256 tile -> 4x16x4 = 256 WGs
  gemm128<2><<<dim3(DIM / 256, SEQ / 128, BATCH), 512, 0, stream>>>(
      P, vT, rowsum, out, SEQ, DIM, SEQ, SEQ, SEQ,
      (size_t)SEQ * SEQ, (size_t)DIM * SEQ, (size_t)SEQ * DIM);
}